// Round 1
// baseline (7187.218 us; speedup 1.0000x reference)
//
#include <hip/hip_runtime.h>
#include <math.h>

#define N_NODES 100000
#define N_EDGES 1600000
#define F_IN    512
#define HD1     64    // 8 heads x 8 dims
#define NHEAD   8
#define NC      40
#define NEG_SLOPE 0.2f
#define NEG_INF_KEY 0x007FFFFFu   // fkey(-inf)

// monotone float->uint transform for atomicMax-based segment max
__device__ __forceinline__ unsigned fkey(float x){
  unsigned b = __float_as_uint(x);
  return (b & 0x80000000u) ? ~b : (b | 0x80000000u);
}
__device__ __forceinline__ float funkey(unsigned k){
  unsigned b = (k & 0x80000000u) ? (k & 0x7FFFFFFFu) : ~k;
  return __uint_as_float(b);
}

__global__ void fill_f32(float* __restrict__ p, int n, float v){
  int i = blockIdx.x*256 + threadIdx.x;
  int stride = gridDim.x*256;
  for(; i<n; i+=stride) p[i]=v;
}
__global__ void fill_u32(unsigned* __restrict__ p, int n, unsigned v){
  int i = blockIdx.x*256 + threadIdx.x;
  int stride = gridDim.x*256;
  for(; i<n; i+=stride) p[i]=v;
}
__global__ void elu_inplace(float* __restrict__ p, int n){
  int i = blockIdx.x*256 + threadIdx.x;
  int stride = gridDim.x*256;
  for(; i<n; i+=stride){ float v=p[i]; p[i] = v>0.f ? v : expm1f(v); }
}

// ---------------- layer-1 GEMM: hs = x@Ws+bs, hd = x@Wd+bd  [N,512]x[512,64]
// block 256 thr: 32 rows x 64 cols, thread = (col c, rowgroup rg of 8 rows)
__global__ __launch_bounds__(256) void gemm1(
    const float* __restrict__ x,
    const float* __restrict__ Ws, const float* __restrict__ bs,
    const float* __restrict__ Wd, const float* __restrict__ bd,
    float* __restrict__ hs, float* __restrict__ hd){
  __shared__ float xs[32][128];   // k-chunk of 128
  int row0 = blockIdx.x * 32;
  int c  = threadIdx.x & 63;
  int rg = threadIdx.x >> 6;      // 0..3
  float acc_s[8], acc_d[8];
  #pragma unroll
  for(int r=0;r<8;r++){ acc_s[r]=0.f; acc_d[r]=0.f; }

  for(int kc=0;kc<4;kc++){
    __syncthreads();
    #pragma unroll
    for(int t=0;t<4;t++){
      int idx = threadIdx.x + t*256;      // 0..1023 float4 slots
      int r  = idx >> 5;                  // 32 float4 per row
      int kq = idx & 31;
      int grow = row0 + r;
      if(grow >= N_NODES) grow = N_NODES-1;
      float4 v = *(const float4*)&x[grow*F_IN + kc*128 + kq*4];
      *(float4*)&xs[r][kq*4] = v;
    }
    __syncthreads();
    #pragma unroll 8
    for(int k4=0;k4<32;k4++){
      float4 xv[8];
      #pragma unroll
      for(int r=0;r<8;r++) xv[r] = *(const float4*)&xs[rg*8+r][k4*4];
      int kb = (kc*128 + k4*4)*64 + c;
      float ws0=Ws[kb], ws1=Ws[kb+64], ws2=Ws[kb+128], ws3=Ws[kb+192];
      float wd0=Wd[kb], wd1=Wd[kb+64], wd2=Wd[kb+128], wd3=Wd[kb+192];
      #pragma unroll
      for(int r=0;r<8;r++){
        acc_s[r]=fmaf(xv[r].x,ws0,acc_s[r]); acc_s[r]=fmaf(xv[r].y,ws1,acc_s[r]);
        acc_s[r]=fmaf(xv[r].z,ws2,acc_s[r]); acc_s[r]=fmaf(xv[r].w,ws3,acc_s[r]);
        acc_d[r]=fmaf(xv[r].x,wd0,acc_d[r]); acc_d[r]=fmaf(xv[r].y,wd1,acc_d[r]);
        acc_d[r]=fmaf(xv[r].z,wd2,acc_d[r]); acc_d[r]=fmaf(xv[r].w,wd3,acc_d[r]);
      }
    }
  }
  float bsv = bs[c], bdv = bd[c];
  #pragma unroll
  for(int r=0;r<8;r++){
    int grow = row0 + rg*8 + r;
    if(grow < N_NODES){
      hs[grow*HD1 + c] = acc_s[r] + bsv;
      hd[grow*HD1 + c] = acc_d[r] + bdv;
    }
  }
}

// ---------------- layer-1 edge pass A: logits + segment max -----------------
__global__ __launch_bounds__(256) void edge_logits1(
    const float* __restrict__ hs, const float* __restrict__ hd,
    const int* __restrict__ src, const int* __restrict__ dst,
    const float* __restrict__ attn, float* __restrict__ logits,
    unsigned* __restrict__ mkey){
  __shared__ float a[64];
  if(threadIdx.x < 64) a[threadIdx.x] = attn[threadIdx.x];
  __syncthreads();
  long long tid = (long long)blockIdx.x*256 + threadIdx.x;
  if(tid >= (long long)N_EDGES*NHEAD) return;
  int e = (int)(tid >> 3), h = (int)(tid & 7);
  int s = src[e], d = dst[e];
  const float4* ps = (const float4*)&hs[s*HD1 + h*8];
  const float4* pd = (const float4*)&hd[d*HD1 + h*8];
  float4 s0=ps[0], s1v=ps[1], d0=pd[0], d1v=pd[1];
  float logit = 0.f, v;
  v=s0.x+d0.x;  v=v>0.f?v:NEG_SLOPE*v; logit=fmaf(v,a[h*8+0],logit);
  v=s0.y+d0.y;  v=v>0.f?v:NEG_SLOPE*v; logit=fmaf(v,a[h*8+1],logit);
  v=s0.z+d0.z;  v=v>0.f?v:NEG_SLOPE*v; logit=fmaf(v,a[h*8+2],logit);
  v=s0.w+d0.w;  v=v>0.f?v:NEG_SLOPE*v; logit=fmaf(v,a[h*8+3],logit);
  v=s1v.x+d1v.x;v=v>0.f?v:NEG_SLOPE*v; logit=fmaf(v,a[h*8+4],logit);
  v=s1v.y+d1v.y;v=v>0.f?v:NEG_SLOPE*v; logit=fmaf(v,a[h*8+5],logit);
  v=s1v.z+d1v.z;v=v>0.f?v:NEG_SLOPE*v; logit=fmaf(v,a[h*8+6],logit);
  v=s1v.w+d1v.w;v=v>0.f?v:NEG_SLOPE*v; logit=fmaf(v,a[h*8+7],logit);
  logits[tid] = logit;
  atomicMax(&mkey[d*NHEAD + h], fkey(logit));
}

// ---------------- layer-1 edge pass B: exp + segment sum --------------------
__global__ __launch_bounds__(256) void edge_softmax1(
    const int* __restrict__ dst, const unsigned* __restrict__ mkey,
    float* __restrict__ logits, float* __restrict__ ssum){
  long long tid = (long long)blockIdx.x*256 + threadIdx.x;
  if(tid >= (long long)N_EDGES*NHEAD) return;
  int e = (int)(tid >> 3), h = (int)(tid & 7);
  int d = dst[e];
  float m = funkey(mkey[d*NHEAD + h]);
  float p = __expf(logits[tid] - m);
  logits[tid] = p;
  atomicAdd(&ssum[d*NHEAD + h], p);
}

// ---------------- layer-1 edge pass C: alpha * hs[src] -> out[dst] ----------
__global__ __launch_bounds__(256) void edge_aggr1(
    const float* __restrict__ hs,
    const int* __restrict__ src, const int* __restrict__ dst,
    const float* __restrict__ logits, const float* __restrict__ ssum,
    float* __restrict__ out){
  long long tid = (long long)blockIdx.x*256 + threadIdx.x;
  if(tid >= (long long)N_EDGES*NHEAD) return;
  int e = (int)(tid >> 3), h = (int)(tid & 7);
  int s = src[e], d = dst[e];
  float alpha = logits[tid] / (ssum[d*NHEAD + h] + 1e-9f);
  const float4* ps = (const float4*)&hs[s*HD1 + h*8];
  float4 v0 = ps[0], v1 = ps[1];
  float* o = &out[d*HD1 + h*8];
  atomicAdd(&o[0], alpha*v0.x); atomicAdd(&o[1], alpha*v0.y);
  atomicAdd(&o[2], alpha*v0.z); atomicAdd(&o[3], alpha*v0.w);
  atomicAdd(&o[4], alpha*v1.x); atomicAdd(&o[5], alpha*v1.y);
  atomicAdd(&o[6], alpha*v1.z); atomicAdd(&o[7], alpha*v1.w);
}

// ---------------- layer-2 GEMM: [N,64]x[64,40] for Ws and Wd ----------------
// block 320 thr: 64 rows x 80 cols (40 s + 40 d), thread = (c80, rg of 16 rows)
__global__ __launch_bounds__(320) void gemm2(
    const float* __restrict__ h,
    const float* __restrict__ Ws, const float* __restrict__ bs,
    const float* __restrict__ Wd, const float* __restrict__ bd,
    float* __restrict__ hs, float* __restrict__ hd){
  __shared__ float xs[64][64];
  int row0 = blockIdx.x * 64;
  int c80 = threadIdx.x % 80;
  int rg  = threadIdx.x / 80;      // 0..3
  for(int idx = threadIdx.x; idx < 1024; idx += 320){
    int r = idx >> 4, kq = idx & 15;
    int grow = row0 + r;
    if(grow >= N_NODES) grow = N_NODES-1;
    *(float4*)&xs[r][kq*4] = *(const float4*)&h[grow*HD1 + kq*4];
  }
  __syncthreads();
  bool is_s = (c80 < NC);
  const float* W = is_s ? Ws : Wd;
  int col = is_s ? c80 : c80 - NC;
  float acc[16];
  #pragma unroll
  for(int r=0;r<16;r++) acc[r]=0.f;
  for(int k=0;k<64;k++){
    float wv = W[k*NC + col];
    #pragma unroll
    for(int r=0;r<16;r++) acc[r] = fmaf(xs[rg*16+r][k], wv, acc[r]);
  }
  float bv = is_s ? bs[col] : bd[col];
  float* dstp = is_s ? hs : hd;
  #pragma unroll
  for(int r=0;r<16;r++){
    int grow = row0 + rg*16 + r;
    if(grow < N_NODES) dstp[grow*NC + col] = acc[r] + bv;
  }
}

// ---------------- layer-2 edge passes (H=1, D=40) ---------------------------
__global__ __launch_bounds__(256) void edge_logits2(
    const float* __restrict__ hs, const float* __restrict__ hd,
    const int* __restrict__ src, const int* __restrict__ dst,
    const float* __restrict__ attn, float* __restrict__ logits,
    unsigned* __restrict__ mkey){
  __shared__ float a[NC];
  if(threadIdx.x < NC) a[threadIdx.x] = attn[threadIdx.x];
  __syncthreads();
  int e = blockIdx.x*256 + threadIdx.x;
  if(e >= N_EDGES) return;
  int s = src[e], d = dst[e];
  const float4* ps = (const float4*)&hs[s*NC];
  const float4* pd = (const float4*)&hd[d*NC];
  float logit = 0.f;
  #pragma unroll
  for(int q=0;q<10;q++){
    float4 av = ps[q]; float4 bv = pd[q];
    float v;
    v=av.x+bv.x; v=v>0.f?v:NEG_SLOPE*v; logit=fmaf(v,a[q*4+0],logit);
    v=av.y+bv.y; v=v>0.f?v:NEG_SLOPE*v; logit=fmaf(v,a[q*4+1],logit);
    v=av.z+bv.z; v=v>0.f?v:NEG_SLOPE*v; logit=fmaf(v,a[q*4+2],logit);
    v=av.w+bv.w; v=v>0.f?v:NEG_SLOPE*v; logit=fmaf(v,a[q*4+3],logit);
  }
  logits[e] = logit;
  atomicMax(&mkey[d], fkey(logit));
}

__global__ __launch_bounds__(256) void edge_softmax2(
    const int* __restrict__ dst, const unsigned* __restrict__ mkey,
    float* __restrict__ logits, float* __restrict__ ssum){
  int e = blockIdx.x*256 + threadIdx.x;
  if(e >= N_EDGES) return;
  int d = dst[e];
  float p = __expf(logits[e] - funkey(mkey[d]));
  logits[e] = p;
  atomicAdd(&ssum[d], p);
}

__global__ __launch_bounds__(256) void edge_aggr2(
    const float* __restrict__ hs,
    const int* __restrict__ src, const int* __restrict__ dst,
    const float* __restrict__ logits, const float* __restrict__ ssum,
    float* __restrict__ out){
  int e = blockIdx.x*256 + threadIdx.x;
  if(e >= N_EDGES) return;
  int s = src[e], d = dst[e];
  float alpha = logits[e] / (ssum[d] + 1e-9f);
  const float4* ps = (const float4*)&hs[s*NC];
  float* o = &out[d*NC];
  #pragma unroll
  for(int q=0;q<10;q++){
    float4 v = ps[q];
    atomicAdd(&o[q*4+0], alpha*v.x);
    atomicAdd(&o[q*4+1], alpha*v.y);
    atomicAdd(&o[q*4+2], alpha*v.z);
    atomicAdd(&o[q*4+3], alpha*v.w);
  }
}

extern "C" void kernel_launch(void* const* d_in, const int* in_sizes, int n_in,
                              void* d_out, int out_size, void* d_ws, size_t ws_size,
                              hipStream_t stream) {
  const float* x   = (const float*)d_in[0];
  const int*   src = (const int*)  d_in[1];
  const int*   dst = (const int*)  d_in[2];
  const float* W1s = (const float*)d_in[3];
  const float* b1s = (const float*)d_in[4];
  const float* W1d = (const float*)d_in[5];
  const float* b1d = (const float*)d_in[6];
  const float* a1  = (const float*)d_in[7];
  const float* W2s = (const float*)d_in[8];
  const float* b2s = (const float*)d_in[9];
  const float* W2d = (const float*)d_in[10];
  const float* b2d = (const float*)d_in[11];
  const float* a2  = (const float*)d_in[12];
  float* out = (float*)d_out;

  // workspace layout (floats)
  float* ws = (float*)d_ws;
  float*    hs1     = ws;                       // 6.4M
  float*    hd1     = ws + 6400000;             // 6.4M
  float*    h1      = ws + 12800000;            // 6.4M  (layer-1 out, then elu)
  unsigned* m1      = (unsigned*)(ws + 19200000); // 800k
  float*    s1      = ws + 20000000;            // 800k
  float*    logits1 = ws + 20800000;            // 12.8M
  // layer-2 reuse (safe: written only after their sources are dead)
  float*    hs2     = hd1;                      // 4M <= 6.4M
  float*    hd2     = logits1;                  // 4M
  float*    logits2 = logits1 + 4000000;        // 1.6M
  unsigned* m2      = (unsigned*)(logits1 + 5600000); // 100k
  float*    s2      = logits1 + 5700000;        // 100k

  const int EH = N_EDGES * NHEAD;               // 12.8M
  dim3 b256(256);

  // ---- init layer-1 accumulators
  fill_f32<<<1024, b256, 0, stream>>>(h1, N_NODES*HD1, 0.f);
  fill_f32<<<256,  b256, 0, stream>>>(s1, N_NODES*NHEAD, 0.f);
  fill_u32<<<256,  b256, 0, stream>>>(m1, N_NODES*NHEAD, NEG_INF_KEY);

  // ---- layer 1
  gemm1<<<N_NODES/32, b256, 0, stream>>>(x, W1s, b1s, W1d, b1d, hs1, hd1);
  edge_logits1 <<<EH/256, b256, 0, stream>>>(hs1, hd1, src, dst, a1, logits1, m1);
  edge_softmax1<<<EH/256, b256, 0, stream>>>(dst, m1, logits1, s1);
  edge_aggr1   <<<EH/256, b256, 0, stream>>>(hs1, src, dst, logits1, s1, h1);
  elu_inplace  <<<1024, b256, 0, stream>>>(h1, N_NODES*HD1);

  // ---- layer 2
  gemm2<<<(N_NODES+63)/64, dim3(320), 0, stream>>>(h1, W2s, b2s, W2d, b2d, hs2, hd2);
  fill_u32<<<128, b256, 0, stream>>>(m2, N_NODES, NEG_INF_KEY);
  fill_f32<<<128, b256, 0, stream>>>(s2, N_NODES, 0.f);
  fill_f32<<<1024, b256, 0, stream>>>(out, N_NODES*NC, 0.f);
  edge_logits2 <<<N_EDGES/256, b256, 0, stream>>>(hs2, hd2, src, dst, a2, logits2, m2);
  edge_softmax2<<<N_EDGES/256, b256, 0, stream>>>(dst, m2, logits2, s2);
  edge_aggr2   <<<N_EDGES/256, b256, 0, stream>>>(hs2, src, dst, logits2, s2, out);
}

// Round 2
// 1145.421 us; speedup vs baseline: 6.2747x; 6.2747x over previous
//
#include <hip/hip_runtime.h>
#include <math.h>

#define N_NODES 100000
#define N_EDGES 1600000
#define F_IN    512
#define HD1     64    // 8 heads x 8 dims
#define NHEAD   8
#define NC      40
#define NEG_SLOPE 0.2f

// ---------------------------------------------------------------- utilities
__global__ void fill_i32(int* __restrict__ p, int n, int v){
  int i = blockIdx.x*256 + threadIdx.x;
  int stride = gridDim.x*256;
  for(; i<n; i+=stride) p[i]=v;
}

// ---------------------------------------------------------------- CSR build
__global__ __launch_bounds__(256) void hist_dst(const int* __restrict__ dst,
                                                int* __restrict__ deg){
  int e = blockIdx.x*256 + threadIdx.x;
  if(e >= N_EDGES) return;
  atomicAdd(&deg[dst[e]], 1);
}

// 3-phase exclusive scan of deg[N_NODES] -> row (and cursor copy)
__global__ __launch_bounds__(256) void scan1(const int* __restrict__ deg,
                                             int* __restrict__ row,
                                             int* __restrict__ bsum){
  __shared__ int sm[256];
  int t = threadIdx.x;
  int base = blockIdx.x*1024 + t*4;
  int v0 = base+0<N_NODES ? deg[base+0] : 0;
  int v1 = base+1<N_NODES ? deg[base+1] : 0;
  int v2 = base+2<N_NODES ? deg[base+2] : 0;
  int v3 = base+3<N_NODES ? deg[base+3] : 0;
  int tsum = v0+v1+v2+v3;
  sm[t] = tsum; __syncthreads();
  for(int off=1; off<256; off<<=1){
    int x = (t>=off) ? sm[t-off] : 0;
    __syncthreads();
    sm[t] += x;
    __syncthreads();
  }
  int excl = sm[t] - tsum;
  if(t==255) bsum[blockIdx.x] = sm[255];
  if(base+0<N_NODES) row[base+0] = excl;
  if(base+1<N_NODES) row[base+1] = excl+v0;
  if(base+2<N_NODES) row[base+2] = excl+v0+v1;
  if(base+3<N_NODES) row[base+3] = excl+v0+v1+v2;
}

__global__ __launch_bounds__(128) void scan2(int* __restrict__ bsum, int nb){
  __shared__ int sm[128];
  int t = threadIdx.x;
  int v = (t<nb) ? bsum[t] : 0;
  sm[t] = v; __syncthreads();
  for(int off=1; off<128; off<<=1){
    int x = (t>=off) ? sm[t-off] : 0;
    __syncthreads();
    sm[t] += x;
    __syncthreads();
  }
  if(t<nb) bsum[t] = sm[t] - v;   // exclusive block offsets
}

__global__ __launch_bounds__(256) void scan3(int* __restrict__ row,
                                             const int* __restrict__ bsum,
                                             int* __restrict__ cur){
  int i = blockIdx.x*256 + threadIdx.x;
  if(i >= N_NODES) return;
  int r = row[i] + bsum[i>>10];
  row[i] = r; cur[i] = r;
}

// scatter src ids into dst-grouped order
__global__ __launch_bounds__(256) void scatter_edges(const int* __restrict__ src,
                                                     const int* __restrict__ dst,
                                                     int* __restrict__ cur,
                                                     int* __restrict__ esrc){
  int e = blockIdx.x*256 + threadIdx.x;
  if(e >= N_EDGES) return;
  int pos = atomicAdd(&cur[dst[e]], 1);
  esrc[pos] = src[e];
}

// ---------------- layer-1 GEMM: hs = x@Ws+bs, hd = x@Wd+bd  [N,512]x[512,64]
__global__ __launch_bounds__(256) void gemm1(
    const float* __restrict__ x,
    const float* __restrict__ Ws, const float* __restrict__ bs,
    const float* __restrict__ Wd, const float* __restrict__ bd,
    float* __restrict__ hs, float* __restrict__ hd){
  __shared__ float xs[32][128];   // k-chunk of 128
  int row0 = blockIdx.x * 32;
  int c  = threadIdx.x & 63;
  int rg = threadIdx.x >> 6;      // 0..3
  float acc_s[8], acc_d[8];
  #pragma unroll
  for(int r=0;r<8;r++){ acc_s[r]=0.f; acc_d[r]=0.f; }

  for(int kc=0;kc<4;kc++){
    __syncthreads();
    #pragma unroll
    for(int t=0;t<4;t++){
      int idx = threadIdx.x + t*256;      // 0..1023 float4 slots
      int r  = idx >> 5;                  // 32 float4 per row
      int kq = idx & 31;
      int grow = row0 + r;
      if(grow >= N_NODES) grow = N_NODES-1;
      float4 v = *(const float4*)&x[grow*F_IN + kc*128 + kq*4];
      *(float4*)&xs[r][kq*4] = v;
    }
    __syncthreads();
    #pragma unroll 8
    for(int k4=0;k4<32;k4++){
      float4 xv[8];
      #pragma unroll
      for(int r=0;r<8;r++) xv[r] = *(const float4*)&xs[rg*8+r][k4*4];
      int kb = (kc*128 + k4*4)*64 + c;
      float ws0=Ws[kb], ws1=Ws[kb+64], ws2=Ws[kb+128], ws3=Ws[kb+192];
      float wd0=Wd[kb], wd1=Wd[kb+64], wd2=Wd[kb+128], wd3=Wd[kb+192];
      #pragma unroll
      for(int r=0;r<8;r++){
        acc_s[r]=fmaf(xv[r].x,ws0,acc_s[r]); acc_s[r]=fmaf(xv[r].y,ws1,acc_s[r]);
        acc_s[r]=fmaf(xv[r].z,ws2,acc_s[r]); acc_s[r]=fmaf(xv[r].w,ws3,acc_s[r]);
        acc_d[r]=fmaf(xv[r].x,wd0,acc_d[r]); acc_d[r]=fmaf(xv[r].y,wd1,acc_d[r]);
        acc_d[r]=fmaf(xv[r].z,wd2,acc_d[r]); acc_d[r]=fmaf(xv[r].w,wd3,acc_d[r]);
      }
    }
  }
  float bsv = bs[c], bdv = bd[c];
  #pragma unroll
  for(int r=0;r<8;r++){
    int grow = row0 + rg*8 + r;
    if(grow < N_NODES){
      hs[grow*HD1 + c] = acc_s[r] + bsv;
      hd[grow*HD1 + c] = acc_d[r] + bdv;
    }
  }
}

// ---------------- layer-1 fused attention: one wave per dst node ------------
// lane = h*8+dim. Online softmax per head (replicated over the head's 8 lanes).
// Epilogue: ELU fused. No atomics.
__global__ __launch_bounds__(256) void node_attn1(
    const float* __restrict__ hs, const float* __restrict__ hd,
    const int* __restrict__ row, const int* __restrict__ deg,
    const int* __restrict__ esrc, const float* __restrict__ attn,
    float* __restrict__ out){
  int node = blockIdx.x*4 + (threadIdx.x>>6);
  int lane = threadIdx.x & 63;
  if(node >= N_NODES) return;
  float hdv = hd[node*HD1 + lane];
  float av  = attn[lane];
  int st = row[node], en = st + deg[node];
  float m = -1e30f, sum = 0.f, acc = 0.f;
  for(int i=st; i<en; i++){
    int s = esrc[i];
    float hsv = hs[s*HD1 + lane];
    float v = hsv + hdv;
    v = v>0.f ? v : NEG_SLOPE*v;
    float t = v * av;
    t += __shfl_xor(t,1); t += __shfl_xor(t,2); t += __shfl_xor(t,4);
    float mn = fmaxf(m, t);
    float eo = __expf(m - mn);
    float p  = __expf(t - mn);
    sum = sum*eo + p;
    acc = acc*eo + p*hsv;
    m = mn;
  }
  float r = acc / (sum + 1e-9f);
  r = r>0.f ? r : expm1f(r);           // ELU fused
  out[node*HD1 + lane] = r;
}

// ---------------- layer-2 GEMM: [N,64]x[64,40] for Ws and Wd ----------------
__global__ __launch_bounds__(320) void gemm2(
    const float* __restrict__ h,
    const float* __restrict__ Ws, const float* __restrict__ bs,
    const float* __restrict__ Wd, const float* __restrict__ bd,
    float* __restrict__ hs, float* __restrict__ hd){
  __shared__ float xs[64][64];
  int row0 = blockIdx.x * 64;
  int c80 = threadIdx.x % 80;
  int rg  = threadIdx.x / 80;      // 0..3
  for(int idx = threadIdx.x; idx < 1024; idx += 320){
    int r = idx >> 4, kq = idx & 15;
    int grow = row0 + r;
    if(grow >= N_NODES) grow = N_NODES-1;
    *(float4*)&xs[r][kq*4] = *(const float4*)&h[grow*HD1 + kq*4];
  }
  __syncthreads();
  bool is_s = (c80 < NC);
  const float* W = is_s ? Ws : Wd;
  int col = is_s ? c80 : c80 - NC;
  float acc[16];
  #pragma unroll
  for(int r=0;r<16;r++) acc[r]=0.f;
  for(int k=0;k<64;k++){
    float wv = W[k*NC + col];
    #pragma unroll
    for(int r=0;r<16;r++) acc[r] = fmaf(xs[rg*16+r][k], wv, acc[r]);
  }
  float bv = is_s ? bs[col] : bd[col];
  float* dstp = is_s ? hs : hd;
  #pragma unroll
  for(int r=0;r<16;r++){
    int grow = row0 + rg*16 + r;
    if(grow < N_NODES) dstp[grow*NC + col] = acc[r] + bv;
  }
}

// ---------------- layer-2 fused attention: one wave per dst node ------------
// lanes 0..39 hold features; single head -> full-wave reduction for the logit.
__global__ __launch_bounds__(256) void node_attn2(
    const float* __restrict__ hs, const float* __restrict__ hd,
    const int* __restrict__ row, const int* __restrict__ deg,
    const int* __restrict__ esrc, const float* __restrict__ attn,
    float* __restrict__ out){
  int node = blockIdx.x*4 + (threadIdx.x>>6);
  int lane = threadIdx.x & 63;
  if(node >= N_NODES) return;
  bool act = lane < NC;
  float hdv = act ? hd[node*NC + lane] : 0.f;
  float av  = act ? attn[lane] : 0.f;
  int st = row[node], en = st + deg[node];
  float m = -1e30f, sum = 0.f, acc = 0.f;
  for(int i=st; i<en; i++){
    int s = esrc[i];
    float hsv = act ? hs[s*NC + lane] : 0.f;
    float v = hsv + hdv;
    v = v>0.f ? v : NEG_SLOPE*v;
    float t = v * av;     // inactive lanes contribute 0
    t += __shfl_xor(t,1);  t += __shfl_xor(t,2);  t += __shfl_xor(t,4);
    t += __shfl_xor(t,8);  t += __shfl_xor(t,16); t += __shfl_xor(t,32);
    float mn = fmaxf(m, t);
    float eo = __expf(m - mn);
    float p  = __expf(t - mn);
    sum = sum*eo + p;
    acc = acc*eo + p*hsv;
    m = mn;
  }
  if(act) out[node*NC + lane] = acc / (sum + 1e-9f);
}

extern "C" void kernel_launch(void* const* d_in, const int* in_sizes, int n_in,
                              void* d_out, int out_size, void* d_ws, size_t ws_size,
                              hipStream_t stream) {
  const float* x   = (const float*)d_in[0];
  const int*   src = (const int*)  d_in[1];
  const int*   dst = (const int*)  d_in[2];
  const float* W1s = (const float*)d_in[3];
  const float* b1s = (const float*)d_in[4];
  const float* W1d = (const float*)d_in[5];
  const float* b1d = (const float*)d_in[6];
  const float* a1  = (const float*)d_in[7];
  const float* W2s = (const float*)d_in[8];
  const float* b2s = (const float*)d_in[9];
  const float* W2d = (const float*)d_in[10];
  const float* b2d = (const float*)d_in[11];
  const float* a2  = (const float*)d_in[12];
  float* out = (float*)d_out;

  // workspace layout
  float* ws   = (float*)d_ws;
  float* hs1  = ws;                         // 6.4M floats
  float* hd1  = ws + 6400000;               // 6.4M floats
  float* h1   = ws + 12800000;              // 6.4M floats
  int*   deg  = (int*)(ws + 19200000);      // 100k
  int*   row  = deg  + 100000;              // 100k
  int*   cur  = row  + 100000;              // 100k
  int*   bsum = cur  + 100000;              // 128
  int*   esrc = bsum + 128;                 // 1.6M
  // layer-2 reuse (hs1/hd1 dead after node_attn1)
  float* hs2  = hs1;                        // 4M <= 6.4M
  float* hd2  = hd1;                        // 4M <= 6.4M

  dim3 b256(256);
  const int EB = N_EDGES/256;               // 6250 (exact)
  const int NB = (N_NODES+255)/256;         // 391
  const int SB = (N_NODES+1023)/1024;       // 98 scan blocks

  // ---- CSR build (graph identical for both layers)
  fill_i32<<<256, b256, 0, stream>>>(deg, N_NODES, 0);
  hist_dst<<<EB, b256, 0, stream>>>(dst, deg);
  scan1<<<SB, b256, 0, stream>>>(deg, row, bsum);
  scan2<<<1, dim3(128), 0, stream>>>(bsum, SB);
  scan3<<<NB, b256, 0, stream>>>(row, bsum, cur);
  scatter_edges<<<EB, b256, 0, stream>>>(src, dst, cur, esrc);

  // ---- layer 1
  gemm1<<<N_NODES/32, b256, 0, stream>>>(x, W1s, b1s, W1d, b1d, hs1, hd1);
  node_attn1<<<(N_NODES+3)/4, b256, 0, stream>>>(hs1, hd1, row, deg, esrc, a1, h1);

  // ---- layer 2
  gemm2<<<(N_NODES+63)/64, dim3(320), 0, stream>>>(h1, W2s, b2s, W2d, b2d, hs2, hd2);
  node_attn2<<<(N_NODES+3)/4, b256, 0, stream>>>(hs2, hd2, row, deg, esrc, a2, out);
}

// Round 3
// 931.773 us; speedup vs baseline: 7.7135x; 1.2293x over previous
//
#include <hip/hip_runtime.h>
#include <math.h>

#define N_NODES 100000
#define N_EDGES 1600000
#define F_IN    512
#define HD1     64    // 8 heads x 8 dims
#define NHEAD   8
#define NC      40
#define NEG_SLOPE 0.2f

typedef _Float16 h8 __attribute__((ext_vector_type(8)));
typedef float f4 __attribute__((ext_vector_type(4)));

// ---------------------------------------------------------------- utilities
__global__ void fill_i32(int* __restrict__ p, int n, int v){
  int i = blockIdx.x*256 + threadIdx.x;
  int stride = gridDim.x*256;
  for(; i<n; i+=stride) p[i]=v;
}

// weight prep: Bt[n][k] fp16, n = concat(Ws cols, Wd cols)
__global__ __launch_bounds__(256) void conv_w1(const float* __restrict__ Ws,
                                               const float* __restrict__ Wd,
                                               _Float16* __restrict__ btg){
  int idx = blockIdx.x*256 + threadIdx.x;
  if(idx >= 128*512) return;
  int n = idx >> 9, k = idx & 511;
  float v = (n < 64) ? Ws[k*64 + n] : Wd[k*64 + (n-64)];
  btg[idx] = (_Float16)v;
}
__global__ __launch_bounds__(256) void conv_w2(const float* __restrict__ Ws,
                                               const float* __restrict__ Wd,
                                               _Float16* __restrict__ btg){
  int idx = blockIdx.x*256 + threadIdx.x;
  if(idx >= 80*64) return;
  int n = idx >> 6, k = idx & 63;
  float v = (n < 40) ? Ws[k*40 + n] : Wd[k*40 + (n-40)];
  btg[idx] = (_Float16)v;
}

// ---------------------------------------------------------------- CSR build
__global__ __launch_bounds__(256) void hist_dst(const int* __restrict__ dst,
                                                int* __restrict__ deg){
  int e = blockIdx.x*256 + threadIdx.x;
  if(e >= N_EDGES) return;
  atomicAdd(&deg[dst[e]], 1);
}

__global__ __launch_bounds__(256) void scan1(const int* __restrict__ deg,
                                             int* __restrict__ row,
                                             int* __restrict__ bsum){
  __shared__ int sm[256];
  int t = threadIdx.x;
  int base = blockIdx.x*1024 + t*4;
  int v0 = base+0<N_NODES ? deg[base+0] : 0;
  int v1 = base+1<N_NODES ? deg[base+1] : 0;
  int v2 = base+2<N_NODES ? deg[base+2] : 0;
  int v3 = base+3<N_NODES ? deg[base+3] : 0;
  int tsum = v0+v1+v2+v3;
  sm[t] = tsum; __syncthreads();
  for(int off=1; off<256; off<<=1){
    int x = (t>=off) ? sm[t-off] : 0;
    __syncthreads();
    sm[t] += x;
    __syncthreads();
  }
  int excl = sm[t] - tsum;
  if(t==255) bsum[blockIdx.x] = sm[255];
  if(base+0<N_NODES) row[base+0] = excl;
  if(base+1<N_NODES) row[base+1] = excl+v0;
  if(base+2<N_NODES) row[base+2] = excl+v0+v1;
  if(base+3<N_NODES) row[base+3] = excl+v0+v1+v2;
}

__global__ __launch_bounds__(128) void scan2(int* __restrict__ bsum, int nb){
  __shared__ int sm[128];
  int t = threadIdx.x;
  int v = (t<nb) ? bsum[t] : 0;
  sm[t] = v; __syncthreads();
  for(int off=1; off<128; off<<=1){
    int x = (t>=off) ? sm[t-off] : 0;
    __syncthreads();
    sm[t] += x;
    __syncthreads();
  }
  if(t<nb) bsum[t] = sm[t] - v;   // exclusive block offsets
}

__global__ __launch_bounds__(256) void scan3(int* __restrict__ row,
                                             const int* __restrict__ bsum,
                                             int* __restrict__ cur){
  int i = blockIdx.x*256 + threadIdx.x;
  if(i >= N_NODES) return;
  int r = row[i] + bsum[i>>10];
  row[i] = r; cur[i] = r;
}

__global__ __launch_bounds__(256) void scatter_edges(const int* __restrict__ src,
                                                     const int* __restrict__ dst,
                                                     int* __restrict__ cur,
                                                     int* __restrict__ esrc){
  int e = blockIdx.x*256 + threadIdx.x;
  if(e >= N_EDGES) return;
  int pos = atomicAdd(&cur[dst[e]], 1);
  esrc[pos] = src[e];
}

// ---------------- layer-1 GEMM via fp16 MFMA --------------------------------
// C-tile 192x128 per 256-thread block (4 waves, wave = 48 rows x 128 cols).
// B (=[W1s|W1d]^T, [128 n][512 k] fp16) staged in LDS in K-quarters.
// A loaded straight from global x with inline fp32->fp16 convert.
__global__ __launch_bounds__(256) void gemm1_mfma(
    const float* __restrict__ x, const _Float16* __restrict__ btg,
    const float* __restrict__ bs, const float* __restrict__ bd,
    float* __restrict__ hs, float* __restrict__ hd){
  __shared__ _Float16 bt[128*136];   // 34,816 B; +8 pad -> 2-way (free) banks
  int tid = threadIdx.x;
  int lane = tid & 63, w = tid >> 6;
  int l15 = lane & 15, quad = lane >> 4;
  int rbase = blockIdx.x*192 + w*48;
  const float* ap[3];
  #pragma unroll
  for(int mt=0; mt<3; mt++){
    int r = rbase + mt*16 + l15;
    if(r >= N_NODES) r = N_NODES-1;
    ap[mt] = x + r*F_IN + quad*8;
  }
  f4 acc[3][8];
  #pragma unroll
  for(int mt=0;mt<3;mt++)
    #pragma unroll
    for(int t=0;t<8;t++) acc[mt][t] = (f4){0.f,0.f,0.f,0.f};

  for(int kq=0; kq<4; kq++){
    __syncthreads();
    #pragma unroll
    for(int ii=0; ii<8; ii++){          // stage 128x128-k quarter
      int i = tid + ii*256;
      int r = i >> 4, c = i & 15;
      *(float4*)&bt[r*136 + c*8] = *(const float4*)&btg[r*512 + kq*128 + c*8];
    }
    __syncthreads();
    #pragma unroll
    for(int ki=0; ki<4; ki++){
      int kk = kq*128 + ki*32;
      h8 af[3];
      #pragma unroll
      for(int mt=0;mt<3;mt++){
        float4 q0 = *(const float4*)(ap[mt] + kk);
        float4 q1 = *(const float4*)(ap[mt] + kk + 4);
        h8 a;
        a[0]=(_Float16)q0.x; a[1]=(_Float16)q0.y; a[2]=(_Float16)q0.z; a[3]=(_Float16)q0.w;
        a[4]=(_Float16)q1.x; a[5]=(_Float16)q1.y; a[6]=(_Float16)q1.z; a[7]=(_Float16)q1.w;
        af[mt]=a;
      }
      #pragma unroll
      for(int t=0;t<8;t++){
        h8 bf = *(const h8*)&bt[(t*16 + l15)*136 + ki*32 + quad*8];
        #pragma unroll
        for(int mt=0;mt<3;mt++)
          acc[mt][t] = __builtin_amdgcn_mfma_f32_16x16x32_f16(af[mt], bf, acc[mt][t], 0,0,0);
      }
    }
  }
  // epilogue: C/D map col=lane&15, row=quad*4+reg
  #pragma unroll
  for(int t=0;t<8;t++){
    int colg = t*16 + l15;
    float bv; float* op; int c;
    if(colg < 64){ bv = bs[colg]; op = hs; c = colg; }
    else         { bv = bd[colg-64]; op = hd; c = colg-64; }
    #pragma unroll
    for(int mt=0;mt<3;mt++)
      #pragma unroll
      for(int reg=0;reg<4;reg++){
        int rr = rbase + mt*16 + quad*4 + reg;
        if(rr < N_NODES) op[rr*HD1 + c] = acc[mt][t][reg] + bv;
      }
  }
}

// ---------------- layer-2 GEMM via fp16 MFMA (B in registers, no LDS) -------
__global__ __launch_bounds__(256) void gemm2_mfma(
    const _Float16* __restrict__ h1h, const _Float16* __restrict__ btg,
    const float* __restrict__ bs, const float* __restrict__ bd,
    float* __restrict__ hs2, float* __restrict__ hd2){
  int tid = threadIdx.x;
  int lane = tid & 63, w = tid >> 6;
  int l15 = lane & 15, quad = lane >> 4;
  int rbase = blockIdx.x*192 + w*48;
  h8 bf[2][5];
  #pragma unroll
  for(int ks=0;ks<2;ks++)
    #pragma unroll
    for(int t=0;t<5;t++)
      bf[ks][t] = *(const h8*)&btg[(t*16 + l15)*64 + ks*32 + quad*8];
  f4 acc[3][5];
  #pragma unroll
  for(int mt=0;mt<3;mt++)
    #pragma unroll
    for(int t=0;t<5;t++) acc[mt][t] = (f4){0.f,0.f,0.f,0.f};
  #pragma unroll
  for(int mt=0;mt<3;mt++){
    int r = rbase + mt*16 + l15;
    if(r >= N_NODES) r = N_NODES-1;
    const _Float16* ap = h1h + r*HD1 + quad*8;
    #pragma unroll
    for(int ks=0;ks<2;ks++){
      h8 af = *(const h8*)(ap + ks*32);
      #pragma unroll
      for(int t=0;t<5;t++)
        acc[mt][t] = __builtin_amdgcn_mfma_f32_16x16x32_f16(af, bf[ks][t], acc[mt][t], 0,0,0);
    }
  }
  #pragma unroll
  for(int t=0;t<5;t++){
    int colg = t*16 + l15;
    float bv; float* op; int c;
    if(colg < 40){ bv = bs[colg]; op = hs2; c = colg; }
    else         { bv = bd[colg-40]; op = hd2; c = colg-40; }
    #pragma unroll
    for(int mt=0;mt<3;mt++)
      #pragma unroll
      for(int reg=0;reg<4;reg++){
        int rr = rbase + mt*16 + quad*4 + reg;
        if(rr < N_NODES) op[rr*NC + c] = acc[mt][t][reg] + bv;
      }
  }
}

// ---------------- layer-1 fused attention: one wave per dst node ------------
__global__ __launch_bounds__(256) void node_attn1(
    const float* __restrict__ hs, const float* __restrict__ hd,
    const int* __restrict__ row, const int* __restrict__ deg,
    const int* __restrict__ esrc, const float* __restrict__ attn,
    _Float16* __restrict__ out){
  int node = blockIdx.x*4 + (threadIdx.x>>6);
  int lane = threadIdx.x & 63;
  if(node >= N_NODES) return;
  float hdv = hd[node*HD1 + lane];
  float av  = attn[lane];
  int st = row[node], en = st + deg[node];
  float m = -1e30f, sum = 0.f, acc = 0.f;
  for(int i=st; i<en; i++){
    int s = esrc[i];
    float hsv = hs[s*HD1 + lane];
    float v = hsv + hdv;
    v = v>0.f ? v : NEG_SLOPE*v;
    float t = v * av;
    t += __shfl_xor(t,1); t += __shfl_xor(t,2); t += __shfl_xor(t,4);
    float mn = fmaxf(m, t);
    float eo = __expf(m - mn);
    float p  = __expf(t - mn);
    sum = sum*eo + p;
    acc = acc*eo + p*hsv;
    m = mn;
  }
  float r = acc / (sum + 1e-9f);
  r = r>0.f ? r : expm1f(r);           // ELU fused
  out[node*HD1 + lane] = (_Float16)r;  // fp16 for layer-2 MFMA A-operand
}

// ---------------- layer-2 fused attention: one wave per dst node ------------
__global__ __launch_bounds__(256) void node_attn2(
    const float* __restrict__ hs, const float* __restrict__ hd,
    const int* __restrict__ row, const int* __restrict__ deg,
    const int* __restrict__ esrc, const float* __restrict__ attn,
    float* __restrict__ out){
  int node = blockIdx.x*4 + (threadIdx.x>>6);
  int lane = threadIdx.x & 63;
  if(node >= N_NODES) return;
  bool act = lane < NC;
  float hdv = act ? hd[node*NC + lane] : 0.f;
  float av  = act ? attn[lane] : 0.f;
  int st = row[node], en = st + deg[node];
  float m = -1e30f, sum = 0.f, acc = 0.f;
  for(int i=st; i<en; i++){
    int s = esrc[i];
    float hsv = act ? hs[s*NC + lane] : 0.f;
    float v = hsv + hdv;
    v = v>0.f ? v : NEG_SLOPE*v;
    float t = v * av;     // inactive lanes contribute 0
    t += __shfl_xor(t,1);  t += __shfl_xor(t,2);  t += __shfl_xor(t,4);
    t += __shfl_xor(t,8);  t += __shfl_xor(t,16); t += __shfl_xor(t,32);
    float mn = fmaxf(m, t);
    float eo = __expf(m - mn);
    float p  = __expf(t - mn);
    sum = sum*eo + p;
    acc = acc*eo + p*hsv;
    m = mn;
  }
  if(act) out[node*NC + lane] = acc / (sum + 1e-9f);
}

extern "C" void kernel_launch(void* const* d_in, const int* in_sizes, int n_in,
                              void* d_out, int out_size, void* d_ws, size_t ws_size,
                              hipStream_t stream) {
  const float* x   = (const float*)d_in[0];
  const int*   src = (const int*)  d_in[1];
  const int*   dst = (const int*)  d_in[2];
  const float* W1s = (const float*)d_in[3];
  const float* b1s = (const float*)d_in[4];
  const float* W1d = (const float*)d_in[5];
  const float* b1d = (const float*)d_in[6];
  const float* a1  = (const float*)d_in[7];
  const float* W2s = (const float*)d_in[8];
  const float* b2s = (const float*)d_in[9];
  const float* W2d = (const float*)d_in[10];
  const float* b2d = (const float*)d_in[11];
  const float* a2  = (const float*)d_in[12];
  float* out = (float*)d_out;

  // workspace layout (float offsets; all 16B-aligned)
  float* ws    = (float*)d_ws;
  float* hs1   = ws;                              // 6.4M f
  float* hd1   = ws + 6400000;                    // 6.4M f
  _Float16* h1h  = (_Float16*)(ws + 12800000);    // 6.4M halfs
  _Float16* btg1 = (_Float16*)(ws + 16000000);    // 65536 halfs
  _Float16* btg2 = (_Float16*)(ws + 16032768);    // 5120 halfs
  int*   deg  = (int*)(ws + 16035328);            // 100k
  int*   row  = deg  + 100000;
  int*   cur  = row  + 100000;
  int*   bsum = cur  + 100000;                    // 128
  int*   esrc = bsum + 128;                       // 1.6M
  float* hs2  = hs1;                              // layer-2 reuse (4M <= 6.4M)
  float* hd2  = hd1;

  dim3 b256(256);
  const int EB = N_EDGES/256;               // 6250 (exact)
  const int NB = (N_NODES+255)/256;         // 391
  const int SB = (N_NODES+1023)/1024;       // 98 scan blocks
  const int GB = (N_NODES+191)/192;         // 521 gemm blocks

  // ---- weight prep (fp16 transposed concat)
  conv_w1<<<256, b256, 0, stream>>>(W1s, W1d, btg1);
  conv_w2<<<20,  b256, 0, stream>>>(W2s, W2d, btg2);

  // ---- CSR build (graph identical for both layers)
  fill_i32<<<256, b256, 0, stream>>>(deg, N_NODES, 0);
  hist_dst<<<EB, b256, 0, stream>>>(dst, deg);
  scan1<<<SB, b256, 0, stream>>>(deg, row, bsum);
  scan2<<<1, dim3(128), 0, stream>>>(bsum, SB);
  scan3<<<NB, b256, 0, stream>>>(row, bsum, cur);
  scatter_edges<<<EB, b256, 0, stream>>>(src, dst, cur, esrc);

  // ---- layer 1
  gemm1_mfma<<<GB, b256, 0, stream>>>(x, btg1, b1s, b1d, hs1, hd1);
  node_attn1<<<(N_NODES+3)/4, b256, 0, stream>>>(hs1, hd1, row, deg, esrc, a1, h1h);

  // ---- layer 2
  gemm2_mfma<<<GB, b256, 0, stream>>>(h1h, btg2, b2s, b2d, hs2, hd2);
  node_attn2<<<(N_NODES+3)/4, b256, 0, stream>>>(hs2, hd2, row, deg, esrc, a2, out);
}

// Round 4
// 704.166 us; speedup vs baseline: 10.2067x; 1.3232x over previous
//
#include <hip/hip_runtime.h>
#include <math.h>

#define N_NODES 100000
#define N_EDGES 1600000
#define F_IN    512
#define HD1     64    // 8 heads x 8 dims
#define NHEAD   8
#define NC      40
#define NEG_SLOPE 0.2f

typedef _Float16 h8 __attribute__((ext_vector_type(8)));
typedef float f4 __attribute__((ext_vector_type(4)));

// ---------------------------------------------------------------- utilities
__global__ void fill_i32(int* __restrict__ p, int n, int v){
  int i = blockIdx.x*256 + threadIdx.x;
  int stride = gridDim.x*256;
  for(; i<n; i+=stride) p[i]=v;
}

// weight prep: Bt[n][k] fp16, n = concat(Ws cols, Wd cols)
__global__ __launch_bounds__(256) void conv_w1(const float* __restrict__ Ws,
                                               const float* __restrict__ Wd,
                                               _Float16* __restrict__ btg){
  int idx = blockIdx.x*256 + threadIdx.x;
  if(idx >= 128*512) return;
  int n = idx >> 9, k = idx & 511;
  float v = (n < 64) ? Ws[k*64 + n] : Wd[k*64 + (n-64)];
  btg[idx] = (_Float16)v;
}
__global__ __launch_bounds__(256) void conv_w2(const float* __restrict__ Ws,
                                               const float* __restrict__ Wd,
                                               _Float16* __restrict__ btg){
  int idx = blockIdx.x*256 + threadIdx.x;
  if(idx >= 80*64) return;
  int n = idx >> 6, k = idx & 63;
  float v = (n < 40) ? Ws[k*40 + n] : Wd[k*40 + (n-40)];
  btg[idx] = (_Float16)v;
}

// ---------------------------------------------------------------- CSR build
__global__ __launch_bounds__(256) void hist_dst(const int* __restrict__ dst,
                                                int* __restrict__ deg){
  int e = blockIdx.x*256 + threadIdx.x;
  if(e >= N_EDGES) return;
  atomicAdd(&deg[dst[e]], 1);
}

__global__ __launch_bounds__(256) void scan1(const int* __restrict__ deg,
                                             int* __restrict__ row,
                                             int* __restrict__ bsum){
  __shared__ int sm[256];
  int t = threadIdx.x;
  int base = blockIdx.x*1024 + t*4;
  int v0 = base+0<N_NODES ? deg[base+0] : 0;
  int v1 = base+1<N_NODES ? deg[base+1] : 0;
  int v2 = base+2<N_NODES ? deg[base+2] : 0;
  int v3 = base+3<N_NODES ? deg[base+3] : 0;
  int tsum = v0+v1+v2+v3;
  sm[t] = tsum; __syncthreads();
  for(int off=1; off<256; off<<=1){
    int x = (t>=off) ? sm[t-off] : 0;
    __syncthreads();
    sm[t] += x;
    __syncthreads();
  }
  int excl = sm[t] - tsum;
  if(t==255) bsum[blockIdx.x] = sm[255];
  if(base+0<N_NODES) row[base+0] = excl;
  if(base+1<N_NODES) row[base+1] = excl+v0;
  if(base+2<N_NODES) row[base+2] = excl+v0+v1;
  if(base+3<N_NODES) row[base+3] = excl+v0+v1+v2;
}

__global__ __launch_bounds__(128) void scan2(int* __restrict__ bsum, int nb){
  __shared__ int sm[128];
  int t = threadIdx.x;
  int v = (t<nb) ? bsum[t] : 0;
  sm[t] = v; __syncthreads();
  for(int off=1; off<128; off<<=1){
    int x = (t>=off) ? sm[t-off] : 0;
    __syncthreads();
    sm[t] += x;
    __syncthreads();
  }
  if(t<nb) bsum[t] = sm[t] - v;   // exclusive block offsets
}

__global__ __launch_bounds__(256) void scan3(int* __restrict__ row,
                                             const int* __restrict__ bsum,
                                             int* __restrict__ cur){
  int i = blockIdx.x*256 + threadIdx.x;
  if(i >= N_NODES) return;
  int r = row[i] + bsum[i>>10];
  row[i] = r; cur[i] = r;
}

__global__ __launch_bounds__(256) void scatter_edges(const int* __restrict__ src,
                                                     const int* __restrict__ dst,
                                                     int* __restrict__ cur,
                                                     int* __restrict__ esrc){
  int e = blockIdx.x*256 + threadIdx.x;
  if(e >= N_EDGES) return;
  int pos = atomicAdd(&cur[dst[e]], 1);
  esrc[pos] = src[e];
}

// ---------------- layer-1 GEMM via fp16 MFMA (fp16 outputs) -----------------
__global__ __launch_bounds__(256) void gemm1_mfma(
    const float* __restrict__ x, const _Float16* __restrict__ btg,
    const float* __restrict__ bs, const float* __restrict__ bd,
    _Float16* __restrict__ hs, _Float16* __restrict__ hd){
  __shared__ _Float16 bt[128*136];   // 34,816 B; +8 pad
  int tid = threadIdx.x;
  int lane = tid & 63, w = tid >> 6;
  int l15 = lane & 15, quad = lane >> 4;
  int rbase = blockIdx.x*192 + w*48;
  const float* ap[3];
  #pragma unroll
  for(int mt=0; mt<3; mt++){
    int r = rbase + mt*16 + l15;
    if(r >= N_NODES) r = N_NODES-1;
    ap[mt] = x + r*F_IN + quad*8;
  }
  f4 acc[3][8];
  #pragma unroll
  for(int mt=0;mt<3;mt++)
    #pragma unroll
    for(int t=0;t<8;t++) acc[mt][t] = (f4){0.f,0.f,0.f,0.f};

  for(int kq=0; kq<4; kq++){
    __syncthreads();
    #pragma unroll
    for(int ii=0; ii<8; ii++){          // stage 128x128-k quarter
      int i = tid + ii*256;
      int r = i >> 4, c = i & 15;
      *(float4*)&bt[r*136 + c*8] = *(const float4*)&btg[r*512 + kq*128 + c*8];
    }
    __syncthreads();
    #pragma unroll
    for(int ki=0; ki<4; ki++){
      int kk = kq*128 + ki*32;
      h8 af[3];
      #pragma unroll
      for(int mt=0;mt<3;mt++){
        float4 q0 = *(const float4*)(ap[mt] + kk);
        float4 q1 = *(const float4*)(ap[mt] + kk + 4);
        h8 a;
        a[0]=(_Float16)q0.x; a[1]=(_Float16)q0.y; a[2]=(_Float16)q0.z; a[3]=(_Float16)q0.w;
        a[4]=(_Float16)q1.x; a[5]=(_Float16)q1.y; a[6]=(_Float16)q1.z; a[7]=(_Float16)q1.w;
        af[mt]=a;
      }
      #pragma unroll
      for(int t=0;t<8;t++){
        h8 bf = *(const h8*)&bt[(t*16 + l15)*136 + ki*32 + quad*8];
        #pragma unroll
        for(int mt=0;mt<3;mt++)
          acc[mt][t] = __builtin_amdgcn_mfma_f32_16x16x32_f16(af[mt], bf, acc[mt][t], 0,0,0);
      }
    }
  }
  // epilogue: C/D map col=lane&15, row=quad*4+reg
  #pragma unroll
  for(int t=0;t<8;t++){
    int colg = t*16 + l15;
    float bv; _Float16* op; int c;
    if(colg < 64){ bv = bs[colg]; op = hs; c = colg; }
    else         { bv = bd[colg-64]; op = hd; c = colg-64; }
    #pragma unroll
    for(int mt=0;mt<3;mt++)
      #pragma unroll
      for(int reg=0;reg<4;reg++){
        int rr = rbase + mt*16 + quad*4 + reg;
        if(rr < N_NODES) op[rr*HD1 + c] = (_Float16)(acc[mt][t][reg] + bv);
      }
  }
}

// ---------------- layer-2 GEMM via fp16 MFMA (B in registers, fp16 out) -----
__global__ __launch_bounds__(256) void gemm2_mfma(
    const _Float16* __restrict__ h1h, const _Float16* __restrict__ btg,
    const float* __restrict__ bs, const float* __restrict__ bd,
    _Float16* __restrict__ hs2, _Float16* __restrict__ hd2){
  int tid = threadIdx.x;
  int lane = tid & 63, w = tid >> 6;
  int l15 = lane & 15, quad = lane >> 4;
  int rbase = blockIdx.x*192 + w*48;
  h8 bf[2][5];
  #pragma unroll
  for(int ks=0;ks<2;ks++)
    #pragma unroll
    for(int t=0;t<5;t++)
      bf[ks][t] = *(const h8*)&btg[(t*16 + l15)*64 + ks*32 + quad*8];
  f4 acc[3][5];
  #pragma unroll
  for(int mt=0;mt<3;mt++)
    #pragma unroll
    for(int t=0;t<5;t++) acc[mt][t] = (f4){0.f,0.f,0.f,0.f};
  #pragma unroll
  for(int mt=0;mt<3;mt++){
    int r = rbase + mt*16 + l15;
    if(r >= N_NODES) r = N_NODES-1;
    const _Float16* ap = h1h + r*HD1 + quad*8;
    #pragma unroll
    for(int ks=0;ks<2;ks++){
      h8 af = *(const h8*)(ap + ks*32);
      #pragma unroll
      for(int t=0;t<5;t++)
        acc[mt][t] = __builtin_amdgcn_mfma_f32_16x16x32_f16(af, bf[ks][t], acc[mt][t], 0,0,0);
    }
  }
  #pragma unroll
  for(int t=0;t<5;t++){
    int colg = t*16 + l15;
    float bv; _Float16* op; int c;
    if(colg < 40){ bv = bs[colg]; op = hs2; c = colg; }
    else         { bv = bd[colg-40]; op = hd2; c = colg-40; }
    #pragma unroll
    for(int mt=0;mt<3;mt++)
      #pragma unroll
      for(int reg=0;reg<4;reg++){
        int rr = rbase + mt*16 + quad*4 + reg;
        if(rr < N_NODES) op[rr*NC + c] = (_Float16)(acc[mt][t][reg] + bv);
      }
  }
}

// ---------------- layer-1 fused attention: wave/node, 8 edges/iter ----------
// lane = (eslot = lane>>3, head = lane&7); lane computes one (edge,head) logit
// fully in-register; per-head online state reduced across eslots at the end.
__global__ __launch_bounds__(256) void node_attn1(
    const _Float16* __restrict__ hs, const _Float16* __restrict__ hd,
    const int* __restrict__ row, const int* __restrict__ deg,
    const int* __restrict__ esrc, const float* __restrict__ attn,
    _Float16* __restrict__ out){
  int node = blockIdx.x*4 + (threadIdx.x>>6);
  int lane = threadIdx.x & 63;
  if(node >= N_NODES) return;
  int h  = lane & 7;
  int es = lane >> 3;
  h8 hdh = *(const h8*)&hd[node*HD1 + h*8];
  float4 a0 = *(const float4*)&attn[h*8];
  float4 a1 = *(const float4*)&attn[h*8+4];
  float hdv[8], av[8];
  hdv[0]=(float)hdh[0]; hdv[1]=(float)hdh[1]; hdv[2]=(float)hdh[2]; hdv[3]=(float)hdh[3];
  hdv[4]=(float)hdh[4]; hdv[5]=(float)hdh[5]; hdv[6]=(float)hdh[6]; hdv[7]=(float)hdh[7];
  av[0]=a0.x; av[1]=a0.y; av[2]=a0.z; av[3]=a0.w;
  av[4]=a1.x; av[5]=a1.y; av[6]=a1.z; av[7]=a1.w;
  int st = row[node], en = st + deg[node];
  float m = -1e30f, sum = 0.f;
  float acc[8] = {0.f,0.f,0.f,0.f,0.f,0.f,0.f,0.f};
  for(int base = st; base < en; base += 8){
    int idx = base + es;
    bool val = idx < en;
    int s = esrc[val ? idx : st];
    h8 hsh = *(const h8*)&hs[s*HD1 + h*8];
    float hsv[8]; float t = 0.f;
    #pragma unroll
    for(int j=0;j<8;j++){
      hsv[j] = (float)hsh[j];
      float v = hsv[j] + hdv[j];
      v = fmaxf(v, NEG_SLOPE*v);           // leaky-relu (slope<1)
      t = fmaf(v, av[j], t);
    }
    if(!val) t = -1e30f;
    float tm = t;                           // per-head max across eslots
    tm = fmaxf(tm, __shfl_xor(tm,8));
    tm = fmaxf(tm, __shfl_xor(tm,16));
    tm = fmaxf(tm, __shfl_xor(tm,32));
    float mn = fmaxf(m, tm);
    float eo = __expf(m - mn);
    float p  = __expf(t - mn);              // 0 for invalid slots
    sum = sum*eo + p;
    #pragma unroll
    for(int j=0;j<8;j++) acc[j] = fmaf(p, hsv[j], acc[j]*eo);
    m = mn;
  }
  sum += __shfl_xor(sum,8); sum += __shfl_xor(sum,16); sum += __shfl_xor(sum,32);
  #pragma unroll
  for(int j=0;j<8;j++){
    acc[j] += __shfl_xor(acc[j],8);
    acc[j] += __shfl_xor(acc[j],16);
    acc[j] += __shfl_xor(acc[j],32);
  }
  if(es == 0){
    float inv = 1.f / (sum + 1e-9f);
    h8 o;
    #pragma unroll
    for(int j=0;j<8;j++){
      float r = acc[j] * inv;
      r = r>0.f ? r : expm1f(r);            // ELU fused
      o[j] = (_Float16)r;
    }
    *(h8*)&out[node*HD1 + h*8] = o;
  }
}

// ---------------- layer-2 fused attention: wave/node, 8 edges/iter ----------
// lane = (eslot = lane>>3, fgrp = lane&7); fgrp covers features f*5..f*5+4.
__global__ __launch_bounds__(256) void node_attn2(
    const _Float16* __restrict__ hs, const _Float16* __restrict__ hd,
    const int* __restrict__ row, const int* __restrict__ deg,
    const int* __restrict__ esrc, const float* __restrict__ attn,
    float* __restrict__ out){
  int node = blockIdx.x*4 + (threadIdx.x>>6);
  int lane = threadIdx.x & 63;
  if(node >= N_NODES) return;
  int f  = lane & 7;
  int es = lane >> 3;
  float hdv[5], av[5];
  #pragma unroll
  for(int j=0;j<5;j++){
    hdv[j] = (float)hd[node*NC + f*5 + j];
    av[j]  = attn[f*5 + j];
  }
  int st = row[node], en = st + deg[node];
  float m = -1e30f, sum = 0.f;
  float acc[5] = {0.f,0.f,0.f,0.f,0.f};
  for(int base = st; base < en; base += 8){
    int idx = base + es;
    bool val = idx < en;
    int s = esrc[val ? idx : st];
    const _Float16* hp = &hs[s*NC + f*5];
    float hsv[5]; float t = 0.f;
    #pragma unroll
    for(int j=0;j<5;j++){
      hsv[j] = (float)hp[j];
      float v = hsv[j] + hdv[j];
      v = fmaxf(v, NEG_SLOPE*v);
      t = fmaf(v, av[j], t);
    }
    t += __shfl_xor(t,1); t += __shfl_xor(t,2); t += __shfl_xor(t,4);
    if(!val) t = -1e30f;
    float tm = t;
    tm = fmaxf(tm, __shfl_xor(tm,8));
    tm = fmaxf(tm, __shfl_xor(tm,16));
    tm = fmaxf(tm, __shfl_xor(tm,32));
    float mn = fmaxf(m, tm);
    float eo = __expf(m - mn);
    float p  = __expf(t - mn);
    sum = sum*eo + p;
    #pragma unroll
    for(int j=0;j<5;j++) acc[j] = fmaf(p, hsv[j], acc[j]*eo);
    m = mn;
  }
  sum += __shfl_xor(sum,8); sum += __shfl_xor(sum,16); sum += __shfl_xor(sum,32);
  #pragma unroll
  for(int j=0;j<5;j++){
    acc[j] += __shfl_xor(acc[j],8);
    acc[j] += __shfl_xor(acc[j],16);
    acc[j] += __shfl_xor(acc[j],32);
  }
  if(es == 0){
    float inv = 1.f / (sum + 1e-9f);
    #pragma unroll
    for(int j=0;j<5;j++) out[node*NC + f*5 + j] = acc[j]*inv;
  }
}

extern "C" void kernel_launch(void* const* d_in, const int* in_sizes, int n_in,
                              void* d_out, int out_size, void* d_ws, size_t ws_size,
                              hipStream_t stream) {
  const float* x   = (const float*)d_in[0];
  const int*   src = (const int*)  d_in[1];
  const int*   dst = (const int*)  d_in[2];
  const float* W1s = (const float*)d_in[3];
  const float* b1s = (const float*)d_in[4];
  const float* W1d = (const float*)d_in[5];
  const float* b1d = (const float*)d_in[6];
  const float* a1  = (const float*)d_in[7];
  const float* W2s = (const float*)d_in[8];
  const float* b2s = (const float*)d_in[9];
  const float* W2d = (const float*)d_in[10];
  const float* b2d = (const float*)d_in[11];
  const float* a2  = (const float*)d_in[12];
  float* out = (float*)d_out;

  // workspace layout (float-offset arithmetic; all 16B-aligned)
  float* ws = (float*)d_ws;
  _Float16* hs1h = (_Float16*)ws;                  // 6.4M halfs (3.2M f)
  _Float16* hd1h = (_Float16*)(ws + 3200000);      // 6.4M halfs
  _Float16* h1h  = (_Float16*)(ws + 6400000);      // 6.4M halfs
  _Float16* hs2h = (_Float16*)(ws + 9600000);      // 4.0M halfs (2M f)
  _Float16* hd2h = (_Float16*)(ws + 11600000);     // 4.0M halfs
  _Float16* btg1 = (_Float16*)(ws + 13600000);     // 65536 halfs
  _Float16* btg2 = (_Float16*)(ws + 13632768);     // 5120 halfs
  int*   deg  = (int*)(ws + 13635328);             // 100k
  int*   row  = deg  + 100000;
  int*   cur  = row  + 100000;
  int*   bsum = cur  + 100000;                     // 128
  int*   esrc = bsum + 128;                        // 1.6M

  dim3 b256(256);
  const int EB = N_EDGES/256;               // 6250 (exact)
  const int NB = (N_NODES+255)/256;         // 391
  const int SB = (N_NODES+1023)/1024;       // 98 scan blocks
  const int GB = (N_NODES+191)/192;         // 521 gemm blocks

  // ---- weight prep (fp16 transposed concat)
  conv_w1<<<256, b256, 0, stream>>>(W1s, W1d, btg1);
  conv_w2<<<20,  b256, 0, stream>>>(W2s, W2d, btg2);

  // ---- CSR build (graph identical for both layers)
  fill_i32<<<256, b256, 0, stream>>>(deg, N_NODES, 0);
  hist_dst<<<EB, b256, 0, stream>>>(dst, deg);
  scan1<<<SB, b256, 0, stream>>>(deg, row, bsum);
  scan2<<<1, dim3(128), 0, stream>>>(bsum, SB);
  scan3<<<NB, b256, 0, stream>>>(row, bsum, cur);
  scatter_edges<<<EB, b256, 0, stream>>>(src, dst, cur, esrc);

  // ---- layer 1
  gemm1_mfma<<<GB, b256, 0, stream>>>(x, btg1, b1s, b1d, hs1h, hd1h);
  node_attn1<<<(N_NODES+3)/4, b256, 0, stream>>>(hs1h, hd1h, row, deg, esrc, a1, h1h);

  // ---- layer 2
  gemm2_mfma<<<GB, b256, 0, stream>>>(h1h, btg2, b2s, b2d, hs2h, hd2h);
  node_attn2<<<(N_NODES+3)/4, b256, 0, stream>>>(hs2h, hd2h, row, deg, esrc, a2, out);
}

// Round 5
// 630.764 us; speedup vs baseline: 11.3945x; 1.1164x over previous
//
#include <hip/hip_runtime.h>
#include <math.h>

#define N_NODES 100000
#define N_EDGES 1600000
#define F_IN    512
#define HD1     64    // 8 heads x 8 dims
#define NHEAD   8
#define NC      40
#define NEG_SLOPE 0.2f

typedef _Float16 h8 __attribute__((ext_vector_type(8)));
typedef _Float16 h4 __attribute__((ext_vector_type(4)));
typedef float f4 __attribute__((ext_vector_type(4)));

// ---------------------------------------------------------------- utilities
__global__ void fill_i32(int* __restrict__ p, int n, int v){
  int i = blockIdx.x*256 + threadIdx.x;
  int stride = gridDim.x*256;
  for(; i<n; i+=stride) p[i]=v;
}

// weight prep for gemm1: MFMA-fragment-major B.
// frag (kstep 0..15, t 0..7): elem[lane][j] = W[k=kstep*32+(lane>>4)*8+j][n=t*16+(lane&15)]
__global__ __launch_bounds__(256) void conv_w1f(const float* __restrict__ Ws,
                                                const float* __restrict__ Wd,
                                                _Float16* __restrict__ btgf){
  int i = blockIdx.x*256 + threadIdx.x;
  if(i >= 65536) return;
  int j = i & 7, lane = (i>>3)&63, t = (i>>9)&7, kstep = i>>12;
  int k = kstep*32 + (lane>>4)*8 + j;
  int n = t*16 + (lane&15);
  float v = (n < 64) ? Ws[k*64 + n] : Wd[k*64 + (n-64)];
  btgf[i] = (_Float16)v;
}
__global__ __launch_bounds__(256) void conv_w2(const float* __restrict__ Ws,
                                               const float* __restrict__ Wd,
                                               _Float16* __restrict__ btg){
  int idx = blockIdx.x*256 + threadIdx.x;
  if(idx >= 80*64) return;
  int n = idx >> 6, k = idx & 63;
  float v = (n < 40) ? Ws[k*40 + n] : Wd[k*40 + (n-40)];
  btg[idx] = (_Float16)v;
}

// ---------------------------------------------------------------- CSR build
__global__ __launch_bounds__(256) void hist_dst(const int* __restrict__ dst,
                                                int* __restrict__ deg){
  int e = blockIdx.x*256 + threadIdx.x;
  if(e >= N_EDGES) return;
  atomicAdd(&deg[dst[e]], 1);
}

__global__ __launch_bounds__(256) void scan1(const int* __restrict__ deg,
                                             int* __restrict__ row,
                                             int* __restrict__ bsum){
  __shared__ int sm[256];
  int t = threadIdx.x;
  int base = blockIdx.x*1024 + t*4;
  int v0 = base+0<N_NODES ? deg[base+0] : 0;
  int v1 = base+1<N_NODES ? deg[base+1] : 0;
  int v2 = base+2<N_NODES ? deg[base+2] : 0;
  int v3 = base+3<N_NODES ? deg[base+3] : 0;
  int tsum = v0+v1+v2+v3;
  sm[t] = tsum; __syncthreads();
  for(int off=1; off<256; off<<=1){
    int x = (t>=off) ? sm[t-off] : 0;
    __syncthreads();
    sm[t] += x;
    __syncthreads();
  }
  int excl = sm[t] - tsum;
  if(t==255) bsum[blockIdx.x] = sm[255];
  if(base+0<N_NODES) row[base+0] = excl;
  if(base+1<N_NODES) row[base+1] = excl+v0;
  if(base+2<N_NODES) row[base+2] = excl+v0+v1;
  if(base+3<N_NODES) row[base+3] = excl+v0+v1+v2;
}

__global__ __launch_bounds__(128) void scan2(int* __restrict__ bsum, int nb){
  __shared__ int sm[128];
  int t = threadIdx.x;
  int v = (t<nb) ? bsum[t] : 0;
  sm[t] = v; __syncthreads();
  for(int off=1; off<128; off<<=1){
    int x = (t>=off) ? sm[t-off] : 0;
    __syncthreads();
    sm[t] += x;
    __syncthreads();
  }
  if(t<nb) bsum[t] = sm[t] - v;   // exclusive block offsets
}

__global__ __launch_bounds__(256) void scan3(int* __restrict__ row,
                                             const int* __restrict__ bsum,
                                             int* __restrict__ cur){
  int i = blockIdx.x*256 + threadIdx.x;
  if(i >= N_NODES) return;
  int r = row[i] + bsum[i>>10];
  row[i] = r; cur[i] = r;
}

// XCD-sharded scatter: block b -> xcd = b&7 owns dst range [xcd*12500, +12500).
// 8 blocks sweep each 1024-edge chunk; writes stay XCD-local in a 0.8MB window.
__global__ __launch_bounds__(256) void scatter_edges(const int* __restrict__ src,
                                                     const int* __restrict__ dst,
                                                     int* __restrict__ cur,
                                                     int* __restrict__ esrc){
  int xcd = blockIdx.x & 7;
  int lo = xcd*12500, hi = lo + 12500;
  int e = (blockIdx.x >> 3)*1024 + threadIdx.x;
  #pragma unroll
  for(int j=0;j<4;j++, e+=256){
    if(e < N_EDGES){
      int d = dst[e];
      if(d >= lo && d < hi){
        int pos = atomicAdd(&cur[d], 1);
        esrc[pos] = src[e];
      }
    }
  }
}

// ---------------- layer-1 GEMM via fp16 MFMA --------------------------------
// 64x128 C-tile / 256-thread block (wave = 16 rows x 128 cols). A staged in
// double-buffered LDS (fp32->fp16 on the fly, register prefetch of next chunk
// issued before compute). B read as pre-swizzled fragments straight from L2.
__global__ __launch_bounds__(256,4) void gemm1_mfma(
    const float* __restrict__ x, const _Float16* __restrict__ btgf,
    const float* __restrict__ bs, const float* __restrict__ bd,
    _Float16* __restrict__ hs, _Float16* __restrict__ hd){
  __shared__ _Float16 at[2][64*136];   // 2 x 17,408 B
  int tid = threadIdx.x;
  int lane = tid & 63, w = tid >> 6;
  int l15 = lane & 15, quad = lane >> 4;
  int row0 = blockIdx.x * 64;

  f4 acc[8];
  #pragma unroll
  for(int t=0;t<8;t++) acc[t] = (f4){0.f,0.f,0.f,0.f};

  // staging slot: s = tid + j*256 -> r = s>>5 (row), c4 = s&31 (float4 col)
  int sr[8], sc4[8];
  #pragma unroll
  for(int j=0;j<8;j++){
    int s = tid + j*256;
    int r = s >> 5, c4 = s & 31;
    int gr = row0 + r; if(gr >= N_NODES) gr = N_NODES-1;
    sr[j] = gr; sc4[j] = c4;
  }

  float4 pf[8];
  #pragma unroll
  for(int j=0;j<8;j++)
    pf[j] = *(const float4*)&x[sr[j]*F_IN + sc4[j]*4];

  for(int kc=0; kc<4; kc++){
    int buf = kc & 1;
    // convert + store prefetched chunk into LDS
    #pragma unroll
    for(int j=0;j<8;j++){
      int s = tid + j*256;
      int r = s >> 5, c4 = s & 31;
      h4 hv;
      hv[0]=(_Float16)pf[j].x; hv[1]=(_Float16)pf[j].y;
      hv[2]=(_Float16)pf[j].z; hv[3]=(_Float16)pf[j].w;
      *(h4*)&at[buf][r*136 + c4*4] = hv;
    }
    // issue next chunk's global loads (overlap with compute below)
    if(kc < 3){
      #pragma unroll
      for(int j=0;j<8;j++)
        pf[j] = *(const float4*)&x[sr[j]*F_IN + (kc+1)*128 + sc4[j]*4];
    }
    __syncthreads();
    #pragma unroll
    for(int ks=0;ks<4;ks++){
      h8 af = *(const h8*)&at[buf][(w*16+l15)*136 + ks*32 + quad*8];
      int fbase = ((kc*4+ks)*8)*512 + lane*8;
      #pragma unroll
      for(int t=0;t<8;t++){
        h8 bf = *(const h8*)&btgf[fbase + t*512];
        acc[t] = __builtin_amdgcn_mfma_f32_16x16x32_f16(af, bf, acc[t], 0,0,0);
      }
    }
    // single barrier per chunk (store;barrier;compute) — double buffer makes
    // the next store (other buffer) safe against stragglers in this compute.
  }
  // epilogue: C/D map col=lane&15, row=quad*4+reg
  #pragma unroll
  for(int t=0;t<8;t++){
    int colg = t*16 + l15;
    float bv; _Float16* op; int c;
    if(colg < 64){ bv = bs[colg]; op = hs; c = colg; }
    else         { bv = bd[colg-64]; op = hd; c = colg-64; }
    #pragma unroll
    for(int reg=0;reg<4;reg++){
      int rr = row0 + w*16 + quad*4 + reg;
      if(rr < N_NODES) op[rr*HD1 + c] = (_Float16)(acc[t][reg] + bv);
    }
  }
}

// ---------------- layer-2 GEMM via fp16 MFMA (B in registers, fp16 out) -----
__global__ __launch_bounds__(256) void gemm2_mfma(
    const _Float16* __restrict__ h1h, const _Float16* __restrict__ btg,
    const float* __restrict__ bs, const float* __restrict__ bd,
    _Float16* __restrict__ hs2, _Float16* __restrict__ hd2){
  int tid = threadIdx.x;
  int lane = tid & 63, w = tid >> 6;
  int l15 = lane & 15, quad = lane >> 4;
  int rbase = blockIdx.x*192 + w*48;
  h8 bf[2][5];
  #pragma unroll
  for(int ks=0;ks<2;ks++)
    #pragma unroll
    for(int t=0;t<5;t++)
      bf[ks][t] = *(const h8*)&btg[(t*16 + l15)*64 + ks*32 + quad*8];
  f4 acc[3][5];
  #pragma unroll
  for(int mt=0;mt<3;mt++)
    #pragma unroll
    for(int t=0;t<5;t++) acc[mt][t] = (f4){0.f,0.f,0.f,0.f};
  #pragma unroll
  for(int mt=0;mt<3;mt++){
    int r = rbase + mt*16 + l15;
    if(r >= N_NODES) r = N_NODES-1;
    const _Float16* ap = h1h + r*HD1 + quad*8;
    #pragma unroll
    for(int ks=0;ks<2;ks++){
      h8 af = *(const h8*)(ap + ks*32);
      #pragma unroll
      for(int t=0;t<5;t++)
        acc[mt][t] = __builtin_amdgcn_mfma_f32_16x16x32_f16(af, bf[ks][t], acc[mt][t], 0,0,0);
    }
  }
  #pragma unroll
  for(int t=0;t<5;t++){
    int colg = t*16 + l15;
    float bv; _Float16* op; int c;
    if(colg < 40){ bv = bs[colg]; op = hs2; c = colg; }
    else         { bv = bd[colg-40]; op = hd2; c = colg-40; }
    #pragma unroll
    for(int mt=0;mt<3;mt++)
      #pragma unroll
      for(int reg=0;reg<4;reg++){
        int rr = rbase + mt*16 + quad*4 + reg;
        if(rr < N_NODES) op[rr*NC + c] = (_Float16)(acc[mt][t][reg] + bv);
      }
  }
}

// ---------------- layer-1 fused attention: wave/node, 8 edges/iter ----------
__global__ __launch_bounds__(256) void node_attn1(
    const _Float16* __restrict__ hs, const _Float16* __restrict__ hd,
    const int* __restrict__ row, const int* __restrict__ deg,
    const int* __restrict__ esrc, const float* __restrict__ attn,
    _Float16* __restrict__ out){
  int node = blockIdx.x*4 + (threadIdx.x>>6);
  int lane = threadIdx.x & 63;
  if(node >= N_NODES) return;
  int h  = lane & 7;
  int es = lane >> 3;
  h8 hdh = *(const h8*)&hd[node*HD1 + h*8];
  float4 a0 = *(const float4*)&attn[h*8];
  float4 a1 = *(const float4*)&attn[h*8+4];
  float hdv[8], av[8];
  hdv[0]=(float)hdh[0]; hdv[1]=(float)hdh[1]; hdv[2]=(float)hdh[2]; hdv[3]=(float)hdh[3];
  hdv[4]=(float)hdh[4]; hdv[5]=(float)hdh[5]; hdv[6]=(float)hdh[6]; hdv[7]=(float)hdh[7];
  av[0]=a0.x; av[1]=a0.y; av[2]=a0.z; av[3]=a0.w;
  av[4]=a1.x; av[5]=a1.y; av[6]=a1.z; av[7]=a1.w;
  int st = row[node], en = st + deg[node];
  float m = -1e30f, sum = 0.f;
  float acc[8] = {0.f,0.f,0.f,0.f,0.f,0.f,0.f,0.f};
  for(int base = st; base < en; base += 8){
    int idx = base + es;
    bool val = idx < en;
    int s = esrc[val ? idx : st];
    h8 hsh = *(const h8*)&hs[s*HD1 + h*8];
    float hsv[8]; float t = 0.f;
    #pragma unroll
    for(int j=0;j<8;j++){
      hsv[j] = (float)hsh[j];
      float v = hsv[j] + hdv[j];
      v = fmaxf(v, NEG_SLOPE*v);           // leaky-relu (slope<1)
      t = fmaf(v, av[j], t);
    }
    if(!val) t = -1e30f;
    float tm = t;                           // per-head max across eslots
    tm = fmaxf(tm, __shfl_xor(tm,8));
    tm = fmaxf(tm, __shfl_xor(tm,16));
    tm = fmaxf(tm, __shfl_xor(tm,32));
    float mn = fmaxf(m, tm);
    float eo = __expf(m - mn);
    float p  = __expf(t - mn);              // 0 for invalid slots
    sum = sum*eo + p;
    #pragma unroll
    for(int j=0;j<8;j++) acc[j] = fmaf(p, hsv[j], acc[j]*eo);
    m = mn;
  }
  sum += __shfl_xor(sum,8); sum += __shfl_xor(sum,16); sum += __shfl_xor(sum,32);
  #pragma unroll
  for(int j=0;j<8;j++){
    acc[j] += __shfl_xor(acc[j],8);
    acc[j] += __shfl_xor(acc[j],16);
    acc[j] += __shfl_xor(acc[j],32);
  }
  if(es == 0){
    float inv = 1.f / (sum + 1e-9f);
    h8 o;
    #pragma unroll
    for(int j=0;j<8;j++){
      float r = acc[j] * inv;
      r = r>0.f ? r : expm1f(r);            // ELU fused
      o[j] = (_Float16)r;
    }
    *(h8*)&out[node*HD1 + h*8] = o;
  }
}

// ---------------- layer-2 fused attention: wave/node, 8 edges/iter ----------
__global__ __launch_bounds__(256) void node_attn2(
    const _Float16* __restrict__ hs, const _Float16* __restrict__ hd,
    const int* __restrict__ row, const int* __restrict__ deg,
    const int* __restrict__ esrc, const float* __restrict__ attn,
    float* __restrict__ out){
  int node = blockIdx.x*4 + (threadIdx.x>>6);
  int lane = threadIdx.x & 63;
  if(node >= N_NODES) return;
  int f  = lane & 7;
  int es = lane >> 3;
  float hdv[5], av[5];
  #pragma unroll
  for(int j=0;j<5;j++){
    hdv[j] = (float)hd[node*NC + f*5 + j];
    av[j]  = attn[f*5 + j];
  }
  int st = row[node], en = st + deg[node];
  float m = -1e30f, sum = 0.f;
  float acc[5] = {0.f,0.f,0.f,0.f,0.f};
  for(int base = st; base < en; base += 8){
    int idx = base + es;
    bool val = idx < en;
    int s = esrc[val ? idx : st];
    const _Float16* hp = &hs[s*NC + f*5];
    float hsv[5]; float t = 0.f;
    #pragma unroll
    for(int j=0;j<5;j++){
      hsv[j] = (float)hp[j];
      float v = hsv[j] + hdv[j];
      v = fmaxf(v, NEG_SLOPE*v);
      t = fmaf(v, av[j], t);
    }
    t += __shfl_xor(t,1); t += __shfl_xor(t,2); t += __shfl_xor(t,4);
    if(!val) t = -1e30f;
    float tm = t;
    tm = fmaxf(tm, __shfl_xor(tm,8));
    tm = fmaxf(tm, __shfl_xor(tm,16));
    tm = fmaxf(tm, __shfl_xor(tm,32));
    float mn = fmaxf(m, tm);
    float eo = __expf(m - mn);
    float p  = __expf(t - mn);
    sum = sum*eo + p;
    #pragma unroll
    for(int j=0;j<5;j++) acc[j] = fmaf(p, hsv[j], acc[j]*eo);
    m = mn;
  }
  sum += __shfl_xor(sum,8); sum += __shfl_xor(sum,16); sum += __shfl_xor(sum,32);
  #pragma unroll
  for(int j=0;j<5;j++){
    acc[j] += __shfl_xor(acc[j],8);
    acc[j] += __shfl_xor(acc[j],16);
    acc[j] += __shfl_xor(acc[j],32);
  }
  if(es == 0){
    float inv = 1.f / (sum + 1e-9f);
    #pragma unroll
    for(int j=0;j<5;j++) out[node*NC + f*5 + j] = acc[j]*inv;
  }
}

extern "C" void kernel_launch(void* const* d_in, const int* in_sizes, int n_in,
                              void* d_out, int out_size, void* d_ws, size_t ws_size,
                              hipStream_t stream) {
  const float* x   = (const float*)d_in[0];
  const int*   src = (const int*)  d_in[1];
  const int*   dst = (const int*)  d_in[2];
  const float* W1s = (const float*)d_in[3];
  const float* b1s = (const float*)d_in[4];
  const float* W1d = (const float*)d_in[5];
  const float* b1d = (const float*)d_in[6];
  const float* a1  = (const float*)d_in[7];
  const float* W2s = (const float*)d_in[8];
  const float* b2s = (const float*)d_in[9];
  const float* W2d = (const float*)d_in[10];
  const float* b2d = (const float*)d_in[11];
  const float* a2  = (const float*)d_in[12];
  float* out = (float*)d_out;

  // workspace layout (float-offset arithmetic; all 16B-aligned)
  float* ws = (float*)d_ws;
  _Float16* hs1h = (_Float16*)ws;                  // 6.4M halfs (3.2M f)
  _Float16* hd1h = (_Float16*)(ws + 3200000);      // 6.4M halfs
  _Float16* h1h  = (_Float16*)(ws + 6400000);      // 6.4M halfs
  _Float16* hs2h = (_Float16*)(ws + 9600000);      // 4.0M halfs (2M f)
  _Float16* hd2h = (_Float16*)(ws + 11600000);     // 4.0M halfs
  _Float16* btg1 = (_Float16*)(ws + 13600000);     // 65536 halfs (frag-major)
  _Float16* btg2 = (_Float16*)(ws + 13632768);     // 5120 halfs
  int*   deg  = (int*)(ws + 13635328);             // 100k
  int*   row  = deg  + 100000;
  int*   cur  = row  + 100000;
  int*   bsum = cur  + 100000;                     // 128
  int*   esrc = bsum + 128;                        // 1.6M

  dim3 b256(256);
  const int EB = N_EDGES/256;               // 6250 (exact)
  const int NB = (N_NODES+255)/256;         // 391
  const int SB = (N_NODES+1023)/1024;       // 98 scan blocks
  const int G1 = (N_NODES+63)/64;           // 1563 gemm1 blocks
  const int G2 = (N_NODES+191)/192;         // 521 gemm2 blocks
  const int XB = ((N_EDGES+1023)/1024)*8;   // 12504 scatter blocks

  // ---- weight prep
  conv_w1f<<<256, b256, 0, stream>>>(W1s, W1d, btg1);
  conv_w2 <<<20,  b256, 0, stream>>>(W2s, W2d, btg2);

  // ---- CSR build (graph identical for both layers)
  fill_i32<<<256, b256, 0, stream>>>(deg, N_NODES, 0);
  hist_dst<<<EB, b256, 0, stream>>>(dst, deg);
  scan1<<<SB, b256, 0, stream>>>(deg, row, bsum);
  scan2<<<1, dim3(128), 0, stream>>>(bsum, SB);
  scan3<<<NB, b256, 0, stream>>>(row, bsum, cur);
  scatter_edges<<<XB, b256, 0, stream>>>(src, dst, cur, esrc);

  // ---- layer 1
  gemm1_mfma<<<G1, b256, 0, stream>>>(x, btg1, b1s, b1d, hs1h, hd1h);
  node_attn1<<<(N_NODES+3)/4, b256, 0, stream>>>(hs1h, hd1h, row, deg, esrc, a1, h1h);

  // ---- layer 2
  gemm2_mfma<<<G2, b256, 0, stream>>>(h1h, btg2, b2s, b2d, hs2h, hd2h);
  node_attn2<<<(N_NODES+3)/4, b256, 0, stream>>>(hs2h, hd2h, row, deg, esrc, a2, out);
}